// Round 4
// baseline (236.662 us; speedup 1.0000x reference)
//
#include <hip/hip_runtime.h>
#include <hip/hip_bf16.h>

#define S_LEN 512
#define EMB   512
#define NHEAD 8
#define DPH   64
#define NREL  3
#define BATCH 8

__device__ __forceinline__ float bf2f(unsigned short u) {
    union { unsigned int i; float f; } cv;
    cv.i = ((unsigned int)u) << 16;
    return cv.f;
}
__device__ __forceinline__ unsigned short f2bf(float f) {
    __hip_bfloat16 h = __float2bfloat16(f);
    return *reinterpret_cast<unsigned short*>(&h);
}

// ---------------------------------------------------------------------------
// Projection GEMM: C[M,N] (bf16 ws) = A[M,K] (f32) @ W[K,N] (f32) + bias (f32)
// M=4096 N=512 K=512. 64x64 tile, 256 threads, 4x4 micro-tile.
// ---------------------------------------------------------------------------
__global__ __launch_bounds__(256) void gemm_x(
    const float* __restrict__ A,
    const float* __restrict__ W,
    const float* __restrict__ bias,
    unsigned short* __restrict__ out)
{
    const int n0 = blockIdx.x * 64;
    const int m0 = blockIdx.y * 64;
    const int tid = threadIdx.x;
    const int tx = tid & 15, ty = tid >> 4;

    __shared__ float As[64][68];   // As[k][m]
    __shared__ float Bs[64][68];   // Bs[k][n]

    float acc[4][4] = {};

    for (int k0 = 0; k0 < EMB; k0 += 64) {
        __syncthreads();
        #pragma unroll
        for (int it = 0; it < 4; ++it) {
            int c = it * 256 + tid;
            int r = c >> 4, d0 = (c & 15) * 4;
            float4 av = *reinterpret_cast<const float4*>(A + (size_t)(m0 + r) * EMB + k0 + d0);
            As[d0+0][r] = av.x; As[d0+1][r] = av.y; As[d0+2][r] = av.z; As[d0+3][r] = av.w;
            float4 bv = *reinterpret_cast<const float4*>(W + (size_t)(k0 + r) * EMB + n0 + d0);
            *reinterpret_cast<float4*>(&Bs[r][d0]) = bv;
        }
        __syncthreads();

        for (int kk = 0; kk < 64; ++kk) {
            float4 a = *reinterpret_cast<const float4*>(&As[kk][ty * 4]);
            float4 b = *reinterpret_cast<const float4*>(&Bs[kk][tx * 4]);
            float av[4] = {a.x, a.y, a.z, a.w};
            float bv[4] = {b.x, b.y, b.z, b.w};
            #pragma unroll
            for (int i = 0; i < 4; ++i)
                #pragma unroll
                for (int j = 0; j < 4; ++j)
                    acc[i][j] = fmaf(av[i], bv[j], acc[i][j]);
        }
    }

    float bj[4];
    #pragma unroll
    for (int j = 0; j < 4; ++j) bj[j] = bias[n0 + tx * 4 + j];
    #pragma unroll
    for (int i = 0; i < 4; ++i) {
        ushort4 o;
        o.x = f2bf(acc[i][0] + bj[0]);
        o.y = f2bf(acc[i][1] + bj[1]);
        o.z = f2bf(acc[i][2] + bj[2]);
        o.w = f2bf(acc[i][3] + bj[3]);
        *reinterpret_cast<ushort4*>(out + (size_t)(m0 + ty * 4 + i) * EMB + n0 + tx * 4) = o;
    }
}

// ---------------------------------------------------------------------------
// Output GEMM: C[M,N] (f32, d_out) = A[M,K] (bf16 ws) @ W[K,N] (f32) + bias
// ---------------------------------------------------------------------------
__global__ __launch_bounds__(256) void gemm_o(
    const unsigned short* __restrict__ A,
    const float* __restrict__ W,
    const float* __restrict__ bias,
    float* __restrict__ out)
{
    const int n0 = blockIdx.x * 64;
    const int m0 = blockIdx.y * 64;
    const int tid = threadIdx.x;
    const int tx = tid & 15, ty = tid >> 4;

    __shared__ float As[64][68];   // As[k][m]
    __shared__ float Bs[64][68];   // Bs[k][n]

    float acc[4][4] = {};

    const int lr = tid >> 3;        // 0..31
    const int lc = (tid & 7) * 8;   // 0..56

    for (int k0 = 0; k0 < EMB; k0 += 64) {
        __syncthreads();
        #pragma unroll
        for (int half = 0; half < 2; ++half) {
            const int rr = lr + half * 32;
            const ushort4* ap = reinterpret_cast<const ushort4*>(A + (size_t)(m0 + rr) * EMB + k0 + lc);
            ushort4 a0 = ap[0], a1 = ap[1];
            As[lc+0][rr] = bf2f(a0.x); As[lc+1][rr] = bf2f(a0.y);
            As[lc+2][rr] = bf2f(a0.z); As[lc+3][rr] = bf2f(a0.w);
            As[lc+4][rr] = bf2f(a1.x); As[lc+5][rr] = bf2f(a1.y);
            As[lc+6][rr] = bf2f(a1.z); As[lc+7][rr] = bf2f(a1.w);
        }
        #pragma unroll
        for (int it = 0; it < 4; ++it) {
            int c = it * 256 + tid;
            int r = c >> 4, d0 = (c & 15) * 4;
            float4 bv = *reinterpret_cast<const float4*>(W + (size_t)(k0 + r) * EMB + n0 + d0);
            *reinterpret_cast<float4*>(&Bs[r][d0]) = bv;
        }
        __syncthreads();

        for (int kk = 0; kk < 64; ++kk) {
            float4 a = *reinterpret_cast<const float4*>(&As[kk][ty * 4]);
            float4 b = *reinterpret_cast<const float4*>(&Bs[kk][tx * 4]);
            float av[4] = {a.x, a.y, a.z, a.w};
            float bv[4] = {b.x, b.y, b.z, b.w};
            #pragma unroll
            for (int i = 0; i < 4; ++i)
                #pragma unroll
                for (int j = 0; j < 4; ++j)
                    acc[i][j] = fmaf(av[i], bv[j], acc[i][j]);
        }
    }

    float bj[4];
    #pragma unroll
    for (int j = 0; j < 4; ++j) bj[j] = bias[n0 + tx * 4 + j];
    #pragma unroll
    for (int i = 0; i < 4; ++i) {
        float4 o = make_float4(acc[i][0] + bj[0], acc[i][1] + bj[1],
                               acc[i][2] + bj[2], acc[i][3] + bj[3]);
        *reinterpret_cast<float4*>(out + (size_t)(m0 + ty * 4 + i) * EMB + n0 + tx * 4) = o;
    }
}

// ---------------------------------------------------------------------------
// Relation-aware flash attention. q/k/v in ws as bf16; out (ws) bf16.
// Block = one (b, h, 64-q-row tile). 256 threads, 4x4 micro-tiles.
// ---------------------------------------------------------------------------
__global__ __launch_bounds__(256) void attn_kernel(
    const unsigned short* __restrict__ qb,
    const unsigned short* __restrict__ kb,
    const unsigned short* __restrict__ vb,
    const int* __restrict__ rel,
    const float* __restrict__ rel_k, const float* __restrict__ rel_v,
    unsigned short* __restrict__ ob)
{
    const int s0 = blockIdx.x * 64;
    const int h  = blockIdx.y;
    const int b  = blockIdx.z;
    const int tid = threadIdx.x;
    const int tx = tid & 15, ty = tid >> 4;
    const int lr = tid >> 3;        // 0..31
    const int lc = (tid & 7) * 8;   // 0..56

    __shared__ float Qst[64][68];   // [d][row]
    __shared__ float Kst[64][68];   // [d][trow]
    __shared__ float Vs [64][68];   // [trow][d]
    __shared__ float Pst[64][68];   // [t][row]
    __shared__ float qrel_s[64][4]; // [row][rel]
    __shared__ float relv_s[NREL][64];

    const unsigned short* qsrc = qb + ((size_t)(b * S_LEN + s0)) * EMB + h * DPH;
    #pragma unroll
    for (int half = 0; half < 2; ++half) {
        const int rr = lr + half * 32;
        const ushort4* ap = reinterpret_cast<const ushort4*>(qsrc + (size_t)rr * EMB + lc);
        ushort4 a0 = ap[0], a1 = ap[1];
        Qst[lc+0][rr] = bf2f(a0.x); Qst[lc+1][rr] = bf2f(a0.y);
        Qst[lc+2][rr] = bf2f(a0.z); Qst[lc+3][rr] = bf2f(a0.w);
        Qst[lc+4][rr] = bf2f(a1.x); Qst[lc+5][rr] = bf2f(a1.y);
        Qst[lc+6][rr] = bf2f(a1.z); Qst[lc+7][rr] = bf2f(a1.w);
    }
    if (tid < NREL * 64) {
        int rr = tid >> 6, d = tid & 63;
        relv_s[rr][d] = rel_v[rr * DPH + d];
    }
    __syncthreads();
    if (tid < 192) {
        int r = tid / 3, rr = tid - 3 * (tid / 3);
        float s = 0.f;
        for (int d = 0; d < DPH; ++d) s += Qst[d][r] * rel_k[rr * DPH + d];
        qrel_s[r][rr] = s;
    }
    // first loop-top __syncthreads makes qrel_s visible

    float m_run[4], l_run[4], acc[4][4] = {}, es[4][NREL] = {};
    #pragma unroll
    for (int i = 0; i < 4; ++i) { m_run[i] = -1e30f; l_run[i] = 0.f; }

    const unsigned short* ksrc = kb + ((size_t)b * S_LEN) * EMB + h * DPH;
    const unsigned short* vsrc = vb + ((size_t)b * S_LEN) * EMB + h * DPH;
    const int*   rrow = rel + ((size_t)(b * S_LEN + s0)) * S_LEN;
    const float scale = 0.125f;

    for (int tt = 0; tt < 8; ++tt) {
        const int t0 = tt * 64;
        __syncthreads();   // prev PV done before overwriting K/V
        #pragma unroll
        for (int half = 0; half < 2; ++half) {
            const int rr = lr + half * 32;
            const ushort4* kp = reinterpret_cast<const ushort4*>(ksrc + (size_t)(t0 + rr) * EMB + lc);
            ushort4 k0v = kp[0], k1v = kp[1];
            Kst[lc+0][rr] = bf2f(k0v.x); Kst[lc+1][rr] = bf2f(k0v.y);
            Kst[lc+2][rr] = bf2f(k0v.z); Kst[lc+3][rr] = bf2f(k0v.w);
            Kst[lc+4][rr] = bf2f(k1v.x); Kst[lc+5][rr] = bf2f(k1v.y);
            Kst[lc+6][rr] = bf2f(k1v.z); Kst[lc+7][rr] = bf2f(k1v.w);
            const ushort4* vp = reinterpret_cast<const ushort4*>(vsrc + (size_t)(t0 + rr) * EMB + lc);
            ushort4 v0 = vp[0], v1 = vp[1];
            float4 f0 = make_float4(bf2f(v0.x), bf2f(v0.y), bf2f(v0.z), bf2f(v0.w));
            float4 f1 = make_float4(bf2f(v1.x), bf2f(v1.y), bf2f(v1.z), bf2f(v1.w));
            *reinterpret_cast<float4*>(&Vs[rr][lc])     = f0;
            *reinterpret_cast<float4*>(&Vs[rr][lc + 4]) = f1;
        }
        __syncthreads();

        float sc[4][4] = {};
        for (int d = 0; d < DPH; ++d) {
            float4 a  = *reinterpret_cast<const float4*>(&Qst[d][ty * 4]);
            float4 kf = *reinterpret_cast<const float4*>(&Kst[d][tx * 4]);
            float av[4] = {a.x, a.y, a.z, a.w};
            float kv[4] = {kf.x, kf.y, kf.z, kf.w};
            #pragma unroll
            for (int i = 0; i < 4; ++i)
                #pragma unroll
                for (int j = 0; j < 4; ++j)
                    sc[i][j] = fmaf(av[i], kv[j], sc[i][j]);
        }

        #pragma unroll
        for (int i = 0; i < 4; ++i) {
            const int* rp = rrow + (size_t)(ty * 4 + i) * S_LEN + t0 + tx * 4;
            int4 ridx = *reinterpret_cast<const int4*>(rp);
            int rv[4] = {ridx.x, ridx.y, ridx.z, ridx.w};
            #pragma unroll
            for (int j = 0; j < 4; ++j) rv[j] = rv[j] < 0 ? 0 : (rv[j] > 2 ? 2 : rv[j]);
            float mt = -1e30f;
            #pragma unroll
            for (int j = 0; j < 4; ++j) {
                sc[i][j] = (sc[i][j] + qrel_s[ty * 4 + i][rv[j]]) * scale;
                mt = fmaxf(mt, sc[i][j]);
            }
            mt = fmaxf(mt, __shfl_xor(mt, 1));
            mt = fmaxf(mt, __shfl_xor(mt, 2));
            mt = fmaxf(mt, __shfl_xor(mt, 4));
            mt = fmaxf(mt, __shfl_xor(mt, 8));
            float mn = fmaxf(m_run[i], mt);
            float al = __expf(m_run[i] - mn);
            m_run[i] = mn;
            float ps = 0.f;
            #pragma unroll
            for (int j = 0; j < 4; ++j) {
                sc[i][j] = __expf(sc[i][j] - mn);
                ps += sc[i][j];
            }
            ps += __shfl_xor(ps, 1);
            ps += __shfl_xor(ps, 2);
            ps += __shfl_xor(ps, 4);
            ps += __shfl_xor(ps, 8);
            l_run[i] = l_run[i] * al + ps;
            #pragma unroll
            for (int j = 0; j < 4; ++j) acc[i][j] *= al;
            #pragma unroll
            for (int r2 = 0; r2 < NREL; ++r2) {
                float e2 = es[i][r2] * al;
                #pragma unroll
                for (int j = 0; j < 4; ++j) e2 += (rv[j] == r2) ? sc[i][j] : 0.f;
                es[i][r2] = e2;
            }
            #pragma unroll
            for (int j = 0; j < 4; ++j) Pst[tx * 4 + j][ty * 4 + i] = sc[i][j];
        }
        __syncthreads();

        for (int t = 0; t < 64; ++t) {
            float4 p  = *reinterpret_cast<const float4*>(&Pst[t][ty * 4]);
            float4 vv = *reinterpret_cast<const float4*>(&Vs[t][tx * 4]);
            float pv[4]  = {p.x, p.y, p.z, p.w};
            float vv2[4] = {vv.x, vv.y, vv.z, vv.w};
            #pragma unroll
            for (int i = 0; i < 4; ++i)
                #pragma unroll
                for (int j = 0; j < 4; ++j)
                    acc[i][j] = fmaf(pv[i], vv2[j], acc[i][j]);
        }
    }

    #pragma unroll
    for (int i = 0; i < 4; ++i)
        #pragma unroll
        for (int r2 = 0; r2 < NREL; ++r2) {
            float e = es[i][r2];
            e += __shfl_xor(e, 1);
            e += __shfl_xor(e, 2);
            e += __shfl_xor(e, 4);
            e += __shfl_xor(e, 8);
            es[i][r2] = e;
        }

    unsigned short* dst = ob + ((size_t)(b * S_LEN + s0)) * EMB + h * DPH;
    #pragma unroll
    for (int i = 0; i < 4; ++i) {
        float inv = 1.f / l_run[i];
        float o[4];
        #pragma unroll
        for (int j = 0; j < 4; ++j) {
            int d = tx * 4 + j;
            float v = acc[i][j];
            #pragma unroll
            for (int r2 = 0; r2 < NREL; ++r2) v += es[i][r2] * relv_s[r2][d];
            o[j] = v * inv;
        }
        ushort4 ov;
        ov.x = f2bf(o[0]); ov.y = f2bf(o[1]); ov.z = f2bf(o[2]); ov.w = f2bf(o[3]);
        *reinterpret_cast<ushort4*>(dst + (size_t)(ty * 4 + i) * EMB + tx * 4) = ov;
    }
}

extern "C" void kernel_launch(void* const* d_in, const int* in_sizes, int n_in,
                              void* d_out, int out_size, void* d_ws, size_t ws_size,
                              hipStream_t stream) {
    // Inputs confirmed in dict order (round-3 dispatch no-op); keep the
    // alphabetical fallback anyway — it costs nothing.
    int iq=0, ik=1, iv=2, irel=3, iWq=4, ibq=5, iWk=6, ibk=7, iWv=8, ibv=9, iWo=10, ibo=11, irk=12, irv=13;
    if (n_in >= 14 && in_sizes[0] == 512 * 512) {
        iWk=0; iWo=1; iWq=2; iWv=3; ibk=4; ibo=5; ibq=6; ibv=7;
        irel=8; ik=9; iq=10; irk=11; irv=12; iv=13;
    }

    const float* q_in = (const float*)d_in[iq];
    const float* k_in = (const float*)d_in[ik];
    const float* v_in = (const float*)d_in[iv];
    const int*   grel = (const int*)d_in[irel];
    const float* Wq = (const float*)d_in[iWq];
    const float* bq = (const float*)d_in[ibq];
    const float* Wk = (const float*)d_in[iWk];
    const float* bk = (const float*)d_in[ibk];
    const float* Wv = (const float*)d_in[iWv];
    const float* bv = (const float*)d_in[ibv];
    const float* Wo = (const float*)d_in[iWo];
    const float* bo = (const float*)d_in[ibo];
    const float* rk = (const float*)d_in[irk];
    const float* rv = (const float*)d_in[irv];

    // ws: 4 bf16 buffers of [4096][512] -> 4 MB each, 16 MB total.
    unsigned short* qb = (unsigned short*)d_ws;
    unsigned short* kb = qb + (size_t)4096 * 512;
    unsigned short* vb = kb + (size_t)4096 * 512;
    unsigned short* ab = vb + (size_t)4096 * 512;

    dim3 blk(256);
    dim3 gG(8, 64);
    gemm_x<<<gG, blk, 0, stream>>>(q_in, Wq, bq, qb);
    gemm_x<<<gG, blk, 0, stream>>>(k_in, Wk, bk, kb);
    gemm_x<<<gG, blk, 0, stream>>>(v_in, Wv, bv, vb);
    attn_kernel<<<dim3(8, 8, 8), blk, 0, stream>>>(qb, kb, vb, grel, rk, rv, ab);
    gemm_o<<<gG, blk, 0, stream>>>(ab, Wo, bo, (float*)d_out);
}

// Round 5
// 132.760 us; speedup vs baseline: 1.7826x; 1.7826x over previous
//
#include <hip/hip_runtime.h>
#include <hip/hip_bf16.h>

#define S_LEN 512
#define EMB   512
#define NHEAD 8
#define DPH   64
#define NREL  3
#define BATCH 8

typedef __attribute__((ext_vector_type(8))) short bf16x8;
typedef __attribute__((ext_vector_type(4))) float f32x4;

__device__ __forceinline__ float bf2f(unsigned short u) {
    union { unsigned int i; float f; } cv;
    cv.i = ((unsigned int)u) << 16;
    return cv.f;
}
__device__ __forceinline__ unsigned short f2bf(float f) {
    __hip_bfloat16 h = __float2bfloat16(f);
    return *reinterpret_cast<unsigned short*>(&h);
}

// ---------------------------------------------------------------------------
// Weight transpose: Wt[z][n][k] (bf16) = W[z][k][n] (f32), z in {q,k,v,o}.
// grid (8,8,4), 256 threads, 64x64 tiles via LDS.
// ---------------------------------------------------------------------------
__global__ __launch_bounds__(256) void transpose_w(
    const float* __restrict__ Wq, const float* __restrict__ Wk,
    const float* __restrict__ Wv, const float* __restrict__ Wo,
    unsigned short* __restrict__ Wt)
{
    const int z = blockIdx.z;
    const float* W = (z == 0) ? Wq : (z == 1) ? Wk : (z == 2) ? Wv : Wo;
    unsigned short* dst = Wt + (size_t)z * EMB * EMB;

    __shared__ float tile[64][65];
    const int n0 = blockIdx.x * 64, k0 = blockIdx.y * 64;
    const int t = threadIdx.x;
    const int cr = t >> 4, cc = (t & 15) * 4;

    #pragma unroll
    for (int it = 0; it < 4; ++it) {
        int r = cr + it * 16;
        float4 v = *reinterpret_cast<const float4*>(W + (size_t)(k0 + r) * EMB + n0 + cc);
        tile[r][cc + 0] = v.x; tile[r][cc + 1] = v.y;
        tile[r][cc + 2] = v.z; tile[r][cc + 3] = v.w;
    }
    __syncthreads();
    #pragma unroll
    for (int it = 0; it < 4; ++it) {
        int n = cr + it * 16;
        ushort4 o;
        o.x = f2bf(tile[cc + 0][n]); o.y = f2bf(tile[cc + 1][n]);
        o.z = f2bf(tile[cc + 2][n]); o.w = f2bf(tile[cc + 3][n]);
        *reinterpret_cast<ushort4*>(dst + (size_t)(n0 + n) * EMB + k0 + cc) = o;
    }
}

// ---------------------------------------------------------------------------
// MFMA GEMM, 128x64 tile, BK=64, 256 thr = 4 waves (2x2), wave = 64x32.
// A fragments/LDS: [row][k] bf16, XOR-swizzled (row stride 128B, G4 fix).
// B from pre-transposed Wt[n][k]. mfma_f32_16x16x32_bf16.
// Projections: A = f32 HBM, out = bf16 ws. grid (8, 32, 3).
// ---------------------------------------------------------------------------
__global__ __launch_bounds__(256) void gemm_proj_mfma(
    const float* __restrict__ Aq, const float* __restrict__ Ak, const float* __restrict__ Av,
    const unsigned short* __restrict__ Wt,
    const float* __restrict__ bqp, const float* __restrict__ bkp, const float* __restrict__ bvp,
    unsigned short* __restrict__ oq, unsigned short* __restrict__ okp, unsigned short* __restrict__ ov)
{
    const int z = blockIdx.z;
    const float* A = (z == 0) ? Aq : (z == 1) ? Ak : Av;
    const unsigned short* W = Wt + (size_t)z * EMB * EMB;
    const float* bias = (z == 0) ? bqp : (z == 1) ? bkp : bvp;
    unsigned short* out = (z == 0) ? oq : (z == 1) ? okp : ov;

    const int n0 = blockIdx.x * 64;
    const int m0 = blockIdx.y * 128;
    const int tid = threadIdx.x;
    const int lane = tid & 63;
    const int wid = tid >> 6;
    const int wr = wid >> 1, wc = wid & 1;

    __shared__ __align__(16) unsigned char smA[128 * 64 * 2];
    __shared__ __align__(16) unsigned char smB[64 * 64 * 2];

    f32x4 acc[4][2] = {};

    for (int k0 = 0; k0 < EMB; k0 += 64) {
        __syncthreads();
        #pragma unroll
        for (int it = 0; it < 4; ++it) {
            int w = it * 256 + tid;
            int row = w >> 3, kc = w & 7;
            const float* src = A + (size_t)(m0 + row) * EMB + k0 + kc * 8;
            float4 v0 = *reinterpret_cast<const float4*>(src);
            float4 v1 = *reinterpret_cast<const float4*>(src + 4);
            union { unsigned short s[8]; uint4 u; } p;
            p.s[0] = f2bf(v0.x); p.s[1] = f2bf(v0.y); p.s[2] = f2bf(v0.z); p.s[3] = f2bf(v0.w);
            p.s[4] = f2bf(v1.x); p.s[5] = f2bf(v1.y); p.s[6] = f2bf(v1.z); p.s[7] = f2bf(v1.w);
            unsigned byte = ((unsigned)row << 7) + ((unsigned)kc << 4);
            byte ^= (unsigned)((row & 7) << 4);
            *reinterpret_cast<uint4*>(smA + byte) = p.u;
        }
        #pragma unroll
        for (int it = 0; it < 2; ++it) {
            int w = it * 256 + tid;
            int row = w >> 3, kc = w & 7;
            uint4 raw = *reinterpret_cast<const uint4*>(W + (size_t)(n0 + row) * EMB + k0 + kc * 8);
            unsigned byte = ((unsigned)row << 7) + ((unsigned)kc << 4);
            byte ^= (unsigned)((row & 7) << 4);
            *reinterpret_cast<uint4*>(smB + byte) = raw;
        }
        __syncthreads();

        #pragma unroll
        for (int ks = 0; ks < 2; ++ks) {
            bf16x8 bfrag[2];
            #pragma unroll
            for (int ni = 0; ni < 2; ++ni) {
                int col = wc * 32 + ni * 16 + (lane & 15);
                unsigned byte = ((unsigned)col << 7) + (unsigned)(ks << 6) + (unsigned)((lane >> 4) << 4);
                byte ^= (unsigned)((col & 7) << 4);
                bfrag[ni] = *reinterpret_cast<const bf16x8*>(smB + byte);
            }
            #pragma unroll
            for (int mi = 0; mi < 4; ++mi) {
                int row = wr * 64 + mi * 16 + (lane & 15);
                unsigned byte = ((unsigned)row << 7) + (unsigned)(ks << 6) + (unsigned)((lane >> 4) << 4);
                byte ^= (unsigned)((row & 7) << 4);
                bf16x8 afrag = *reinterpret_cast<const bf16x8*>(smA + byte);
                #pragma unroll
                for (int ni = 0; ni < 2; ++ni)
                    acc[mi][ni] = __builtin_amdgcn_mfma_f32_16x16x32_bf16(afrag, bfrag[ni], acc[mi][ni], 0, 0, 0);
            }
        }
    }

    #pragma unroll
    for (int ni = 0; ni < 2; ++ni) {
        int colg = n0 + wc * 32 + ni * 16 + (lane & 15);
        float bj = bias[colg];
        #pragma unroll
        for (int mi = 0; mi < 4; ++mi) {
            int rbase = m0 + wr * 64 + mi * 16 + ((lane >> 4) << 2);
            #pragma unroll
            for (int q = 0; q < 4; ++q)
                out[(size_t)(rbase + q) * EMB + colg] = f2bf(acc[mi][ni][q] + bj);
        }
    }
}

// ---------------------------------------------------------------------------
// Output GEMM: A = bf16 ws (attention out), out = f32 d_out. grid (8, 32).
// ---------------------------------------------------------------------------
__global__ __launch_bounds__(256) void gemm_out_mfma(
    const unsigned short* __restrict__ A,
    const unsigned short* __restrict__ W,   // Wt_o [n][k] bf16
    const float* __restrict__ bias,
    float* __restrict__ out)
{
    const int n0 = blockIdx.x * 64;
    const int m0 = blockIdx.y * 128;
    const int tid = threadIdx.x;
    const int lane = tid & 63;
    const int wid = tid >> 6;
    const int wr = wid >> 1, wc = wid & 1;

    __shared__ __align__(16) unsigned char smA[128 * 64 * 2];
    __shared__ __align__(16) unsigned char smB[64 * 64 * 2];

    f32x4 acc[4][2] = {};

    for (int k0 = 0; k0 < EMB; k0 += 64) {
        __syncthreads();
        #pragma unroll
        for (int it = 0; it < 4; ++it) {
            int w = it * 256 + tid;
            int row = w >> 3, kc = w & 7;
            uint4 raw = *reinterpret_cast<const uint4*>(A + (size_t)(m0 + row) * EMB + k0 + kc * 8);
            unsigned byte = ((unsigned)row << 7) + ((unsigned)kc << 4);
            byte ^= (unsigned)((row & 7) << 4);
            *reinterpret_cast<uint4*>(smA + byte) = raw;
        }
        #pragma unroll
        for (int it = 0; it < 2; ++it) {
            int w = it * 256 + tid;
            int row = w >> 3, kc = w & 7;
            uint4 raw = *reinterpret_cast<const uint4*>(W + (size_t)(n0 + row) * EMB + k0 + kc * 8);
            unsigned byte = ((unsigned)row << 7) + ((unsigned)kc << 4);
            byte ^= (unsigned)((row & 7) << 4);
            *reinterpret_cast<uint4*>(smB + byte) = raw;
        }
        __syncthreads();

        #pragma unroll
        for (int ks = 0; ks < 2; ++ks) {
            bf16x8 bfrag[2];
            #pragma unroll
            for (int ni = 0; ni < 2; ++ni) {
                int col = wc * 32 + ni * 16 + (lane & 15);
                unsigned byte = ((unsigned)col << 7) + (unsigned)(ks << 6) + (unsigned)((lane >> 4) << 4);
                byte ^= (unsigned)((col & 7) << 4);
                bfrag[ni] = *reinterpret_cast<const bf16x8*>(smB + byte);
            }
            #pragma unroll
            for (int mi = 0; mi < 4; ++mi) {
                int row = wr * 64 + mi * 16 + (lane & 15);
                unsigned byte = ((unsigned)row << 7) + (unsigned)(ks << 6) + (unsigned)((lane >> 4) << 4);
                byte ^= (unsigned)((row & 7) << 4);
                bf16x8 afrag = *reinterpret_cast<const bf16x8*>(smA + byte);
                #pragma unroll
                for (int ni = 0; ni < 2; ++ni)
                    acc[mi][ni] = __builtin_amdgcn_mfma_f32_16x16x32_bf16(afrag, bfrag[ni], acc[mi][ni], 0, 0, 0);
            }
        }
    }

    #pragma unroll
    for (int ni = 0; ni < 2; ++ni) {
        int colg = n0 + wc * 32 + ni * 16 + (lane & 15);
        float bj = bias[colg];
        #pragma unroll
        for (int mi = 0; mi < 4; ++mi) {
            int rbase = m0 + wr * 64 + mi * 16 + ((lane >> 4) << 2);
            #pragma unroll
            for (int q = 0; q < 4; ++q)
                out[(size_t)(rbase + q) * EMB + colg] = acc[mi][ni][q] + bj;
        }
    }
}

// ---------------------------------------------------------------------------
// Relation-aware flash attention (unchanged from round 4 — validated).
// ---------------------------------------------------------------------------
__global__ __launch_bounds__(256) void attn_kernel(
    const unsigned short* __restrict__ qb,
    const unsigned short* __restrict__ kb,
    const unsigned short* __restrict__ vb,
    const int* __restrict__ rel,
    const float* __restrict__ rel_k, const float* __restrict__ rel_v,
    unsigned short* __restrict__ ob)
{
    const int s0 = blockIdx.x * 64;
    const int h  = blockIdx.y;
    const int b  = blockIdx.z;
    const int tid = threadIdx.x;
    const int tx = tid & 15, ty = tid >> 4;
    const int lr = tid >> 3;        // 0..31
    const int lc = (tid & 7) * 8;   // 0..56

    __shared__ float Qst[64][68];   // [d][row]
    __shared__ float Kst[64][68];   // [d][trow]
    __shared__ float Vs [64][68];   // [trow][d]
    __shared__ float Pst[64][68];   // [t][row]
    __shared__ float qrel_s[64][4]; // [row][rel]
    __shared__ float relv_s[NREL][64];

    const unsigned short* qsrc = qb + ((size_t)(b * S_LEN + s0)) * EMB + h * DPH;
    #pragma unroll
    for (int half = 0; half < 2; ++half) {
        const int rr = lr + half * 32;
        const ushort4* ap = reinterpret_cast<const ushort4*>(qsrc + (size_t)rr * EMB + lc);
        ushort4 a0 = ap[0], a1 = ap[1];
        Qst[lc+0][rr] = bf2f(a0.x); Qst[lc+1][rr] = bf2f(a0.y);
        Qst[lc+2][rr] = bf2f(a0.z); Qst[lc+3][rr] = bf2f(a0.w);
        Qst[lc+4][rr] = bf2f(a1.x); Qst[lc+5][rr] = bf2f(a1.y);
        Qst[lc+6][rr] = bf2f(a1.z); Qst[lc+7][rr] = bf2f(a1.w);
    }
    if (tid < NREL * 64) {
        int rr = tid >> 6, d = tid & 63;
        relv_s[rr][d] = rel_v[rr * DPH + d];
    }
    __syncthreads();
    if (tid < 192) {
        int r = tid / 3, rr = tid - 3 * (tid / 3);
        float s = 0.f;
        for (int d = 0; d < DPH; ++d) s += Qst[d][r] * rel_k[rr * DPH + d];
        qrel_s[r][rr] = s;
    }

    float m_run[4], l_run[4], acc[4][4] = {}, es[4][NREL] = {};
    #pragma unroll
    for (int i = 0; i < 4; ++i) { m_run[i] = -1e30f; l_run[i] = 0.f; }

    const unsigned short* ksrc = kb + ((size_t)b * S_LEN) * EMB + h * DPH;
    const unsigned short* vsrc = vb + ((size_t)b * S_LEN) * EMB + h * DPH;
    const int*   rrow = rel + ((size_t)(b * S_LEN + s0)) * S_LEN;
    const float scale = 0.125f;

    for (int tt = 0; tt < 8; ++tt) {
        const int t0 = tt * 64;
        __syncthreads();
        #pragma unroll
        for (int half = 0; half < 2; ++half) {
            const int rr = lr + half * 32;
            const ushort4* kp = reinterpret_cast<const ushort4*>(ksrc + (size_t)(t0 + rr) * EMB + lc);
            ushort4 k0v = kp[0], k1v = kp[1];
            Kst[lc+0][rr] = bf2f(k0v.x); Kst[lc+1][rr] = bf2f(k0v.y);
            Kst[lc+2][rr] = bf2f(k0v.z); Kst[lc+3][rr] = bf2f(k0v.w);
            Kst[lc+4][rr] = bf2f(k1v.x); Kst[lc+5][rr] = bf2f(k1v.y);
            Kst[lc+6][rr] = bf2f(k1v.z); Kst[lc+7][rr] = bf2f(k1v.w);
            const ushort4* vp = reinterpret_cast<const ushort4*>(vsrc + (size_t)(t0 + rr) * EMB + lc);
            ushort4 v0 = vp[0], v1 = vp[1];
            float4 f0 = make_float4(bf2f(v0.x), bf2f(v0.y), bf2f(v0.z), bf2f(v0.w));
            float4 f1 = make_float4(bf2f(v1.x), bf2f(v1.y), bf2f(v1.z), bf2f(v1.w));
            *reinterpret_cast<float4*>(&Vs[rr][lc])     = f0;
            *reinterpret_cast<float4*>(&Vs[rr][lc + 4]) = f1;
        }
        __syncthreads();

        float sc[4][4] = {};
        for (int d = 0; d < DPH; ++d) {
            float4 a  = *reinterpret_cast<const float4*>(&Qst[d][ty * 4]);
            float4 kf = *reinterpret_cast<const float4*>(&Kst[d][tx * 4]);
            float av[4] = {a.x, a.y, a.z, a.w};
            float kv[4] = {kf.x, kf.y, kf.z, kf.w};
            #pragma unroll
            for (int i = 0; i < 4; ++i)
                #pragma unroll
                for (int j = 0; j < 4; ++j)
                    sc[i][j] = fmaf(av[i], kv[j], sc[i][j]);
        }

        #pragma unroll
        for (int i = 0; i < 4; ++i) {
            const int* rp = rrow + (size_t)(ty * 4 + i) * S_LEN + t0 + tx * 4;
            int4 ridx = *reinterpret_cast<const int4*>(rp);
            int rv[4] = {ridx.x, ridx.y, ridx.z, ridx.w};
            #pragma unroll
            for (int j = 0; j < 4; ++j) rv[j] = rv[j] < 0 ? 0 : (rv[j] > 2 ? 2 : rv[j]);
            float mt = -1e30f;
            #pragma unroll
            for (int j = 0; j < 4; ++j) {
                sc[i][j] = (sc[i][j] + qrel_s[ty * 4 + i][rv[j]]) * scale;
                mt = fmaxf(mt, sc[i][j]);
            }
            mt = fmaxf(mt, __shfl_xor(mt, 1));
            mt = fmaxf(mt, __shfl_xor(mt, 2));
            mt = fmaxf(mt, __shfl_xor(mt, 4));
            mt = fmaxf(mt, __shfl_xor(mt, 8));
            float mn = fmaxf(m_run[i], mt);
            float al = __expf(m_run[i] - mn);
            m_run[i] = mn;
            float ps = 0.f;
            #pragma unroll
            for (int j = 0; j < 4; ++j) {
                sc[i][j] = __expf(sc[i][j] - mn);
                ps += sc[i][j];
            }
            ps += __shfl_xor(ps, 1);
            ps += __shfl_xor(ps, 2);
            ps += __shfl_xor(ps, 4);
            ps += __shfl_xor(ps, 8);
            l_run[i] = l_run[i] * al + ps;
            #pragma unroll
            for (int j = 0; j < 4; ++j) acc[i][j] *= al;
            #pragma unroll
            for (int r2 = 0; r2 < NREL; ++r2) {
                float e2 = es[i][r2] * al;
                #pragma unroll
                for (int j = 0; j < 4; ++j) e2 += (rv[j] == r2) ? sc[i][j] : 0.f;
                es[i][r2] = e2;
            }
            #pragma unroll
            for (int j = 0; j < 4; ++j) Pst[tx * 4 + j][ty * 4 + i] = sc[i][j];
        }
        __syncthreads();

        for (int t = 0; t < 64; ++t) {
            float4 p  = *reinterpret_cast<const float4*>(&Pst[t][ty * 4]);
            float4 vv = *reinterpret_cast<const float4*>(&Vs[t][tx * 4]);
            float pv[4]  = {p.x, p.y, p.z, p.w};
            float vv2[4] = {vv.x, vv.y, vv.z, vv.w};
            #pragma unroll
            for (int i = 0; i < 4; ++i)
                #pragma unroll
                for (int j = 0; j < 4; ++j)
                    acc[i][j] = fmaf(pv[i], vv2[j], acc[i][j]);
        }
    }

    #pragma unroll
    for (int i = 0; i < 4; ++i)
        #pragma unroll
        for (int r2 = 0; r2 < NREL; ++r2) {
            float e = es[i][r2];
            e += __shfl_xor(e, 1);
            e += __shfl_xor(e, 2);
            e += __shfl_xor(e, 4);
            e += __shfl_xor(e, 8);
            es[i][r2] = e;
        }

    unsigned short* dst = ob + ((size_t)(b * S_LEN + s0)) * EMB + h * DPH;
    #pragma unroll
    for (int i = 0; i < 4; ++i) {
        float inv = 1.f / l_run[i];
        float o[4];
        #pragma unroll
        for (int j = 0; j < 4; ++j) {
            int d = tx * 4 + j;
            float v = acc[i][j];
            #pragma unroll
            for (int r2 = 0; r2 < NREL; ++r2) v += es[i][r2] * relv_s[r2][d];
            o[j] = v * inv;
        }
        ushort4 ov;
        ov.x = f2bf(o[0]); ov.y = f2bf(o[1]); ov.z = f2bf(o[2]); ov.w = f2bf(o[3]);
        *reinterpret_cast<ushort4*>(dst + (size_t)(ty * 4 + i) * EMB + tx * 4) = ov;
    }
}

extern "C" void kernel_launch(void* const* d_in, const int* in_sizes, int n_in,
                              void* d_out, int out_size, void* d_ws, size_t ws_size,
                              hipStream_t stream) {
    int iq=0, ik=1, iv=2, irel=3, iWq=4, ibq=5, iWk=6, ibk=7, iWv=8, ibv=9, iWo=10, ibo=11, irk=12, irv=13;
    if (n_in >= 14 && in_sizes[0] == 512 * 512) {
        iWk=0; iWo=1; iWq=2; iWv=3; ibk=4; ibo=5; ibq=6; ibv=7;
        irel=8; ik=9; iq=10; irk=11; irv=12; iv=13;
    }

    const float* q_in = (const float*)d_in[iq];
    const float* k_in = (const float*)d_in[ik];
    const float* v_in = (const float*)d_in[iv];
    const int*   grel = (const int*)d_in[irel];
    const float* Wq = (const float*)d_in[iWq];
    const float* bq = (const float*)d_in[ibq];
    const float* Wk = (const float*)d_in[iWk];
    const float* bk = (const float*)d_in[ibk];
    const float* Wv = (const float*)d_in[iWv];
    const float* bv = (const float*)d_in[ibv];
    const float* Wo = (const float*)d_in[iWo];
    const float* bo = (const float*)d_in[ibo];
    const float* rk = (const float*)d_in[irk];
    const float* rv = (const float*)d_in[irv];

    // ws: qb,kb,vb,ab bf16 [4096][512] (4 MB each, 16 MB) + Wt bf16 4x[512][512] (2 MB)
    unsigned short* qb = (unsigned short*)d_ws;
    unsigned short* kb = qb + (size_t)4096 * 512;
    unsigned short* vb = kb + (size_t)4096 * 512;
    unsigned short* ab = vb + (size_t)4096 * 512;
    unsigned short* wt = ab + (size_t)4096 * 512;

    dim3 blk(256);
    transpose_w<<<dim3(8, 8, 4), blk, 0, stream>>>(Wq, Wk, Wv, Wo, wt);
    gemm_proj_mfma<<<dim3(8, 32, 3), blk, 0, stream>>>(q_in, k_in, v_in, wt, bq, bk, bv, qb, kb, vb);
    attn_kernel<<<dim3(8, 8, 8), blk, 0, stream>>>(qb, kb, vb, grel, rk, rv, ab);
    gemm_out_mfma<<<dim3(8, 32), blk, 0, stream>>>(ab, wt + (size_t)3 * 512 * 512, bo, (float*)d_out);
}

// Round 7
// 79.326 us; speedup vs baseline: 2.9834x; 1.6736x over previous
//
#include <hip/hip_runtime.h>
#include <hip/hip_bf16.h>

#define S_LEN 512
#define EMB   512
#define NHEAD 8
#define DPH   64
#define NREL  3
#define BATCH 8

typedef __attribute__((ext_vector_type(8))) short bf16x8;
typedef __attribute__((ext_vector_type(4))) float f32x4;

__device__ __forceinline__ float bf2f(unsigned short u) {
    union { unsigned int i; float f; } cv;
    cv.i = ((unsigned int)u) << 16;
    return cv.f;
}
__device__ __forceinline__ unsigned short f2bf(float f) {
    __hip_bfloat16 h = __float2bfloat16(f);
    return *reinterpret_cast<unsigned short*>(&h);
}

// ---------------------------------------------------------------------------
// Weight transpose: Wt[z][n][k] (bf16) = W[z][k][n] (f32), z in {q,k,v,o}.
// ---------------------------------------------------------------------------
__global__ __launch_bounds__(256) void transpose_w(
    const float* __restrict__ Wq, const float* __restrict__ Wk,
    const float* __restrict__ Wv, const float* __restrict__ Wo,
    unsigned short* __restrict__ Wt)
{
    const int z = blockIdx.z;
    const float* W = (z == 0) ? Wq : (z == 1) ? Wk : (z == 2) ? Wv : Wo;
    unsigned short* dst = Wt + (size_t)z * EMB * EMB;

    __shared__ float tile[64][65];
    const int n0 = blockIdx.x * 64, k0 = blockIdx.y * 64;
    const int t = threadIdx.x;
    const int cr = t >> 4, cc = (t & 15) * 4;

    #pragma unroll
    for (int it = 0; it < 4; ++it) {
        int r = cr + it * 16;
        float4 v = *reinterpret_cast<const float4*>(W + (size_t)(k0 + r) * EMB + n0 + cc);
        tile[r][cc + 0] = v.x; tile[r][cc + 1] = v.y;
        tile[r][cc + 2] = v.z; tile[r][cc + 3] = v.w;
    }
    __syncthreads();
    #pragma unroll
    for (int it = 0; it < 4; ++it) {
        int n = cr + it * 16;
        ushort4 o;
        o.x = f2bf(tile[cc + 0][n]); o.y = f2bf(tile[cc + 1][n]);
        o.z = f2bf(tile[cc + 2][n]); o.w = f2bf(tile[cc + 3][n]);
        *reinterpret_cast<ushort4*>(dst + (size_t)(n0 + n) * EMB + k0 + cc) = o;
    }
}

// ---------------------------------------------------------------------------
// MFMA projection GEMM (validated round 5). 128x64 tile, 4 waves 2x2.
// ---------------------------------------------------------------------------
__global__ __launch_bounds__(256) void gemm_proj_mfma(
    const float* __restrict__ Aq, const float* __restrict__ Ak, const float* __restrict__ Av,
    const unsigned short* __restrict__ Wt,
    const float* __restrict__ bqp, const float* __restrict__ bkp, const float* __restrict__ bvp,
    unsigned short* __restrict__ oq, unsigned short* __restrict__ okp, unsigned short* __restrict__ ov)
{
    const int z = blockIdx.z;
    const float* A = (z == 0) ? Aq : (z == 1) ? Ak : Av;
    const unsigned short* W = Wt + (size_t)z * EMB * EMB;
    const float* bias = (z == 0) ? bqp : (z == 1) ? bkp : bvp;
    unsigned short* out = (z == 0) ? oq : (z == 1) ? okp : ov;

    const int n0 = blockIdx.x * 64;
    const int m0 = blockIdx.y * 128;
    const int tid = threadIdx.x;
    const int lane = tid & 63;
    const int wid = tid >> 6;
    const int wr = wid >> 1, wc = wid & 1;

    __shared__ __align__(16) unsigned char smA[128 * 64 * 2];
    __shared__ __align__(16) unsigned char smB[64 * 64 * 2];

    f32x4 acc[4][2] = {};

    for (int k0 = 0; k0 < EMB; k0 += 64) {
        __syncthreads();
        #pragma unroll
        for (int it = 0; it < 4; ++it) {
            int w = it * 256 + tid;
            int row = w >> 3, kc = w & 7;
            const float* src = A + (size_t)(m0 + row) * EMB + k0 + kc * 8;
            float4 v0 = *reinterpret_cast<const float4*>(src);
            float4 v1 = *reinterpret_cast<const float4*>(src + 4);
            union { unsigned short s[8]; uint4 u; } p;
            p.s[0] = f2bf(v0.x); p.s[1] = f2bf(v0.y); p.s[2] = f2bf(v0.z); p.s[3] = f2bf(v0.w);
            p.s[4] = f2bf(v1.x); p.s[5] = f2bf(v1.y); p.s[6] = f2bf(v1.z); p.s[7] = f2bf(v1.w);
            unsigned byte = ((unsigned)row << 7) + ((unsigned)kc << 4);
            byte ^= (unsigned)((row & 7) << 4);
            *reinterpret_cast<uint4*>(smA + byte) = p.u;
        }
        #pragma unroll
        for (int it = 0; it < 2; ++it) {
            int w = it * 256 + tid;
            int row = w >> 3, kc = w & 7;
            uint4 raw = *reinterpret_cast<const uint4*>(W + (size_t)(n0 + row) * EMB + k0 + kc * 8);
            unsigned byte = ((unsigned)row << 7) + ((unsigned)kc << 4);
            byte ^= (unsigned)((row & 7) << 4);
            *reinterpret_cast<uint4*>(smB + byte) = raw;
        }
        __syncthreads();

        #pragma unroll
        for (int ks = 0; ks < 2; ++ks) {
            bf16x8 bfrag[2];
            #pragma unroll
            for (int ni = 0; ni < 2; ++ni) {
                int col = wc * 32 + ni * 16 + (lane & 15);
                unsigned byte = ((unsigned)col << 7) + (unsigned)(ks << 6) + (unsigned)((lane >> 4) << 4);
                byte ^= (unsigned)((col & 7) << 4);
                bfrag[ni] = *reinterpret_cast<const bf16x8*>(smB + byte);
            }
            #pragma unroll
            for (int mi = 0; mi < 4; ++mi) {
                int row = wr * 64 + mi * 16 + (lane & 15);
                unsigned byte = ((unsigned)row << 7) + (unsigned)(ks << 6) + (unsigned)((lane >> 4) << 4);
                byte ^= (unsigned)((row & 7) << 4);
                bf16x8 afrag = *reinterpret_cast<const bf16x8*>(smA + byte);
                #pragma unroll
                for (int ni = 0; ni < 2; ++ni)
                    acc[mi][ni] = __builtin_amdgcn_mfma_f32_16x16x32_bf16(afrag, bfrag[ni], acc[mi][ni], 0, 0, 0);
            }
        }
    }

    #pragma unroll
    for (int ni = 0; ni < 2; ++ni) {
        int colg = n0 + wc * 32 + ni * 16 + (lane & 15);
        float bj = bias[colg];
        #pragma unroll
        for (int mi = 0; mi < 4; ++mi) {
            int rbase = m0 + wr * 64 + mi * 16 + ((lane >> 4) << 2);
            #pragma unroll
            for (int q = 0; q < 4; ++q)
                out[(size_t)(rbase + q) * EMB + colg] = f2bf(acc[mi][ni][q] + bj);
        }
    }
}

// ---------------------------------------------------------------------------
// MFMA output GEMM (validated round 5).
// ---------------------------------------------------------------------------
__global__ __launch_bounds__(256) void gemm_out_mfma(
    const unsigned short* __restrict__ A,
    const unsigned short* __restrict__ W,
    const float* __restrict__ bias,
    float* __restrict__ out)
{
    const int n0 = blockIdx.x * 64;
    const int m0 = blockIdx.y * 128;
    const int tid = threadIdx.x;
    const int lane = tid & 63;
    const int wid = tid >> 6;
    const int wr = wid >> 1, wc = wid & 1;

    __shared__ __align__(16) unsigned char smA[128 * 64 * 2];
    __shared__ __align__(16) unsigned char smB[64 * 64 * 2];

    f32x4 acc[4][2] = {};

    for (int k0 = 0; k0 < EMB; k0 += 64) {
        __syncthreads();
        #pragma unroll
        for (int it = 0; it < 4; ++it) {
            int w = it * 256 + tid;
            int row = w >> 3, kc = w & 7;
            uint4 raw = *reinterpret_cast<const uint4*>(A + (size_t)(m0 + row) * EMB + k0 + kc * 8);
            unsigned byte = ((unsigned)row << 7) + ((unsigned)kc << 4);
            byte ^= (unsigned)((row & 7) << 4);
            *reinterpret_cast<uint4*>(smA + byte) = raw;
        }
        #pragma unroll
        for (int it = 0; it < 2; ++it) {
            int w = it * 256 + tid;
            int row = w >> 3, kc = w & 7;
            uint4 raw = *reinterpret_cast<const uint4*>(W + (size_t)(n0 + row) * EMB + k0 + kc * 8);
            unsigned byte = ((unsigned)row << 7) + ((unsigned)kc << 4);
            byte ^= (unsigned)((row & 7) << 4);
            *reinterpret_cast<uint4*>(smB + byte) = raw;
        }
        __syncthreads();

        #pragma unroll
        for (int ks = 0; ks < 2; ++ks) {
            bf16x8 bfrag[2];
            #pragma unroll
            for (int ni = 0; ni < 2; ++ni) {
                int col = wc * 32 + ni * 16 + (lane & 15);
                unsigned byte = ((unsigned)col << 7) + (unsigned)(ks << 6) + (unsigned)((lane >> 4) << 4);
                byte ^= (unsigned)((col & 7) << 4);
                bfrag[ni] = *reinterpret_cast<const bf16x8*>(smB + byte);
            }
            #pragma unroll
            for (int mi = 0; mi < 4; ++mi) {
                int row = wr * 64 + mi * 16 + (lane & 15);
                unsigned byte = ((unsigned)row << 7) + (unsigned)(ks << 6) + (unsigned)((lane >> 4) << 4);
                byte ^= (unsigned)((row & 7) << 4);
                bf16x8 afrag = *reinterpret_cast<const bf16x8*>(smA + byte);
                #pragma unroll
                for (int ni = 0; ni < 2; ++ni)
                    acc[mi][ni] = __builtin_amdgcn_mfma_f32_16x16x32_bf16(afrag, bfrag[ni], acc[mi][ni], 0, 0, 0);
            }
        }
    }

    #pragma unroll
    for (int ni = 0; ni < 2; ++ni) {
        int colg = n0 + wc * 32 + ni * 16 + (lane & 15);
        float bj = bias[colg];
        #pragma unroll
        for (int mi = 0; mi < 4; ++mi) {
            int rbase = m0 + wr * 64 + mi * 16 + ((lane >> 4) << 2);
            #pragma unroll
            for (int q = 0; q < 4; ++q)
                out[(size_t)(rbase + q) * EMB + colg] = acc[mi][ni][q] + bj;
        }
    }
}

// ---------------------------------------------------------------------------
// MFMA relation-aware flash attention.
// Block = (64 q-rows, h, b), 4 waves; wave owns 16 q-rows.
// Swapped QK^T: mfma(K,Q) -> C[t][s], s = lane&15 -> lane-local row softmax.
// P -> LDS bf16 (per-wave region, XOR swz) -> PV: mfma(P, V^T).
// es[rel] per row: per-lane partial over its t-quarter, cross-reduced
// (shfl_xor 16/32) before the epilogue.  <-- round-6 bugfix
// ---------------------------------------------------------------------------
__global__ __launch_bounds__(256) void attn_mfma(
    const unsigned short* __restrict__ qb,
    const unsigned short* __restrict__ kb,
    const unsigned short* __restrict__ vb,
    const int* __restrict__ rel,
    const float* __restrict__ rel_k, const float* __restrict__ rel_v,
    unsigned short* __restrict__ ob)
{
    const int s0 = blockIdx.x * 64;
    const int h  = blockIdx.y;
    const int b  = blockIdx.z;
    const int tid = threadIdx.x;
    const int lane = tid & 63;
    const int wid = tid >> 6;
    const int sl = lane & 15;      // s (QK) / d (PV) sub-index
    const int tg = lane >> 4;      // 4 lane-groups

    __shared__ __align__(16) unsigned char smQ[64 * 128];
    __shared__ __align__(16) unsigned char smK[64 * 128];
    __shared__ __align__(16) unsigned char smVt[64 * 128];
    __shared__ __align__(16) unsigned char smP[4 * 16 * 128];
    __shared__ float qrel_s[64][4];
    __shared__ float relv_s[NREL][64];

    const unsigned short* qsrc = qb + ((size_t)(b * S_LEN + s0)) * EMB + h * DPH;
    const unsigned short* ksrc = kb + ((size_t)b * S_LEN) * EMB + h * DPH;
    const unsigned short* vsrc = vb + ((size_t)b * S_LEN) * EMB + h * DPH;

    // --- stage Q (64x64 bf16, swizzled) + rel_v ---
    #pragma unroll
    for (int it = 0; it < 2; ++it) {
        int w = it * 256 + tid;
        int row = w >> 3, kc = w & 7;
        uint4 raw = *reinterpret_cast<const uint4*>(qsrc + (size_t)row * EMB + kc * 8);
        unsigned byte = ((unsigned)row << 7) + ((unsigned)kc << 4);
        byte ^= (unsigned)((row & 7) << 4);
        *reinterpret_cast<uint4*>(smQ + byte) = raw;
    }
    if (tid < NREL * 64) {
        int rr = tid >> 6, d = tid & 63;
        relv_s[rr][d] = rel_v[rr * DPH + d];
    }
    __syncthreads();

    // --- qrel[s][r] = q_s . rel_k[r] ---
    if (tid < 192) {
        int r = tid / 3, rr = tid - 3 * (tid / 3);
        float s = 0.f;
        #pragma unroll
        for (int dc = 0; dc < 32; ++dc) {
            unsigned byte = ((unsigned)r << 7) + (unsigned)(dc << 2);
            byte ^= (unsigned)((r & 7) << 4);
            unsigned u = *reinterpret_cast<const unsigned*>(smQ + byte);
            s += bf2f((unsigned short)(u & 0xffff)) * rel_k[rr * DPH + dc * 2]
               + bf2f((unsigned short)(u >> 16))   * rel_k[rr * DPH + dc * 2 + 1];
        }
        qrel_s[r][rr] = s;
    }
    // visibility of qrel_s: first loop-top __syncthreads

    // --- Q fragments (col = s = lane&15, k = ks*32 + tg*8) ---
    bf16x8 qfrag[2];
    #pragma unroll
    for (int ks = 0; ks < 2; ++ks) {
        int row = wid * 16 + sl;
        unsigned byte = ((unsigned)row << 7) + (unsigned)(ks << 6) + (unsigned)(tg << 4);
        byte ^= (unsigned)((row & 7) << 4);
        qfrag[ks] = *reinterpret_cast<const bf16x8*>(smQ + byte);
    }

    const int* rrow_s = rel + ((size_t)(b * S_LEN + s0 + wid * 16 + sl)) * S_LEN;
    const int srow = wid * 16 + sl;
    const unsigned pbase = (unsigned)(wid * 2048);
    const float scale = 0.125f;

    float m_run = -1e30f, l_run = 0.f;
    float es[NREL] = {};
    f32x4 acc_pv[4] = {};

    for (int tt = 0; tt < 8; ++tt) {
        const int t0 = tt * 64;
        __syncthreads();   // prev PV reads of smK/smVt done

        // stage K tile [t][d]
        #pragma unroll
        for (int it = 0; it < 2; ++it) {
            int w = it * 256 + tid;
            int row = w >> 3, kc = w & 7;
            uint4 raw = *reinterpret_cast<const uint4*>(ksrc + (size_t)(t0 + row) * EMB + kc * 8);
            unsigned byte = ((unsigned)row << 7) + ((unsigned)kc << 4);
            byte ^= (unsigned)((row & 7) << 4);
            *reinterpret_cast<uint4*>(smK + byte) = raw;
        }
        // stage V^T tile [d][t]
        {
            int t = tid >> 2, c = tid & 3;
            union { uint4 u[2]; unsigned short s[16]; } p;
            const unsigned short* vr = vsrc + (size_t)(t0 + t) * EMB + c * 16;
            p.u[0] = *reinterpret_cast<const uint4*>(vr);
            p.u[1] = *reinterpret_cast<const uint4*>(vr + 8);
            #pragma unroll
            for (int j = 0; j < 16; ++j) {
                int d = c * 16 + j;
                unsigned byte = ((unsigned)d << 7) + (unsigned)(t << 1);
                byte ^= (unsigned)((d & 7) << 4);
                *reinterpret_cast<unsigned short*>(smVt + byte) = p.s[j];
            }
        }
        __syncthreads();

        // QK^T: C[t][s], 4 t-subtiles x 2 k-halves
        f32x4 sacc[4] = {};
        #pragma unroll
        for (int ks = 0; ks < 2; ++ks) {
            #pragma unroll
            for (int t4 = 0; t4 < 4; ++t4) {
                int trow = t4 * 16 + sl;
                unsigned byte = ((unsigned)trow << 7) + (unsigned)(ks << 6) + (unsigned)(tg << 4);
                byte ^= (unsigned)((trow & 7) << 4);
                bf16x8 kf = *reinterpret_cast<const bf16x8*>(smK + byte);
                sacc[t4] = __builtin_amdgcn_mfma_f32_16x16x32_bf16(kf, qfrag[ks], sacc[t4], 0, 0, 0);
            }
        }

        // rel bias + row max
        int rvv[4][4];
        float mt = -1e30f;
        #pragma unroll
        for (int t4 = 0; t4 < 4; ++t4) {
            int4 ridx = *reinterpret_cast<const int4*>(rrow_s + t0 + t4 * 16 + tg * 4);
            int rv[4] = {ridx.x, ridx.y, ridx.z, ridx.w};
            #pragma unroll
            for (int j = 0; j < 4; ++j) {
                int r = rv[j]; r = r < 0 ? 0 : (r > 2 ? 2 : r);
                rvv[t4][j] = r;
                float v = (sacc[t4][j] + qrel_s[srow][r]) * scale;
                sacc[t4][j] = v;
                mt = fmaxf(mt, v);
            }
        }
        mt = fmaxf(mt, __shfl_xor(mt, 16));
        mt = fmaxf(mt, __shfl_xor(mt, 32));

        float mn = fmaxf(m_run, mt);
        float al = __expf(m_run - mn);
        m_run = mn;

        float ps = 0.f;
        #pragma unroll
        for (int t4 = 0; t4 < 4; ++t4)
            #pragma unroll
            for (int j = 0; j < 4; ++j) {
                float p = __expf(sacc[t4][j] - mn);
                sacc[t4][j] = p;
                ps += p;
            }
        float pst = ps;
        pst += __shfl_xor(pst, 16);
        pst += __shfl_xor(pst, 32);
        l_run = l_run * al + pst;

        #pragma unroll
        for (int r2 = 0; r2 < NREL; ++r2) {
            float e2 = es[r2] * al;
            #pragma unroll
            for (int t4 = 0; t4 < 4; ++t4)
                #pragma unroll
                for (int j = 0; j < 4; ++j)
                    e2 += (rvv[t4][j] == r2) ? sacc[t4][j] : 0.f;
            es[r2] = e2;
        }

        // rescale acc_pv (rows s' = tg*4+reg need al of that row)
        float al_s[4];
        #pragma unroll
        for (int r = 0; r < 4; ++r) al_s[r] = __shfl(al, tg * 4 + r);
        #pragma unroll
        for (int dt = 0; dt < 4; ++dt)
            #pragma unroll
            for (int r = 0; r < 4; ++r) acc_pv[dt][r] *= al_s[r];

        // P -> LDS bf16 (per-wave region; same-wave write->read, DS in-order)
        #pragma unroll
        for (int t4 = 0; t4 < 4; ++t4) {
            #pragma unroll
            for (int pr = 0; pr < 2; ++pr) {
                unsigned u = (unsigned)f2bf(sacc[t4][2 * pr]) |
                             ((unsigned)f2bf(sacc[t4][2 * pr + 1]) << 16);
                unsigned byte = pbase + ((unsigned)sl << 7) + (unsigned)(t4 * 32 + tg * 8 + pr * 4);
                byte ^= (unsigned)((sl & 7) << 4);
                *reinterpret_cast<unsigned*>(smP + byte) = u;
            }
        }

        // PV: acc[s][d] += P[s][t] V[t][d]
        #pragma unroll
        for (int ks = 0; ks < 2; ++ks) {
            unsigned pbyte = pbase + ((unsigned)sl << 7) + (unsigned)(ks << 6) + (unsigned)(tg << 4);
            pbyte ^= (unsigned)((sl & 7) << 4);
            bf16x8 pf = *reinterpret_cast<const bf16x8*>(smP + pbyte);
            #pragma unroll
            for (int dt = 0; dt < 4; ++dt) {
                int d = dt * 16 + sl;
                unsigned vbyte = ((unsigned)d << 7) + (unsigned)(ks << 6) + (unsigned)(tg << 4);
                vbyte ^= (unsigned)((d & 7) << 4);
                bf16x8 vf = *reinterpret_cast<const bf16x8*>(smVt + vbyte);
                acc_pv[dt] = __builtin_amdgcn_mfma_f32_16x16x32_bf16(pf, vf, acc_pv[dt], 0, 0, 0);
            }
        }
    }

    // --- round-6 fix: es is a per-lane partial over this lane's t-quarter;
    //     sum across the 4 tg lane-groups before redistribution. ---
    #pragma unroll
    for (int r2 = 0; r2 < NREL; ++r2) {
        es[r2] += __shfl_xor(es[r2], 16);
        es[r2] += __shfl_xor(es[r2], 32);
    }

    // epilogue: redistribute l/es to PV row layout, add es . rel_v, store
    float l_s[4], es_s[NREL][4];
    #pragma unroll
    for (int r = 0; r < 4; ++r) {
        l_s[r] = __shfl(l_run, tg * 4 + r);
        #pragma unroll
        for (int r2 = 0; r2 < NREL; ++r2) es_s[r2][r] = __shfl(es[r2], tg * 4 + r);
    }

    unsigned short* dst = ob + ((size_t)(b * S_LEN + s0 + wid * 16)) * EMB + h * DPH;
    #pragma unroll
    for (int dt = 0; dt < 4; ++dt) {
        int d = dt * 16 + sl;
        float rv0 = relv_s[0][d], rv1 = relv_s[1][d], rv2 = relv_s[2][d];
        #pragma unroll
        for (int r = 0; r < 4; ++r) {
            int srowo = tg * 4 + r;
            float o = acc_pv[dt][r] + es_s[0][r] * rv0 + es_s[1][r] * rv1 + es_s[2][r] * rv2;
            o /= l_s[r];
            dst[(size_t)srowo * EMB + d] = f2bf(o);
        }
    }
}

extern "C" void kernel_launch(void* const* d_in, const int* in_sizes, int n_in,
                              void* d_out, int out_size, void* d_ws, size_t ws_size,
                              hipStream_t stream) {
    int iq=0, ik=1, iv=2, irel=3, iWq=4, ibq=5, iWk=6, ibk=7, iWv=8, ibv=9, iWo=10, ibo=11, irk=12, irv=13;
    if (n_in >= 14 && in_sizes[0] == 512 * 512) {
        iWk=0; iWo=1; iWq=2; iWv=3; ibk=4; ibo=5; ibq=6; ibv=7;
        irel=8; ik=9; iq=10; irk=11; irv=12; iv=13;
    }

    const float* q_in = (const float*)d_in[iq];
    const float* k_in = (const float*)d_in[ik];
    const float* v_in = (const float*)d_in[iv];
    const int*   grel = (const int*)d_in[irel];
    const float* Wq = (const float*)d_in[iWq];
    const float* bq = (const float*)d_in[ibq];
    const float* Wk = (const float*)d_in[iWk];
    const float* bk = (const float*)d_in[ibk];
    const float* Wv = (const float*)d_in[iWv];
    const float* bv = (const float*)d_in[ibv];
    const float* Wo = (const float*)d_in[iWo];
    const float* bo = (const float*)d_in[ibo];
    const float* rk = (const float*)d_in[irk];
    const float* rv = (const float*)d_in[irv];

    unsigned short* qb = (unsigned short*)d_ws;
    unsigned short* kb = qb + (size_t)4096 * 512;
    unsigned short* vb = kb + (size_t)4096 * 512;
    unsigned short* ab = vb + (size_t)4096 * 512;
    unsigned short* wt = ab + (size_t)4096 * 512;

    dim3 blk(256);
    transpose_w<<<dim3(8, 8, 4), blk, 0, stream>>>(Wq, Wk, Wv, Wo, wt);
    gemm_proj_mfma<<<dim3(8, 32, 3), blk, 0, stream>>>(q_in, k_in, v_in, wt, bq, bk, bv, qb, kb, vb);
    attn_mfma<<<dim3(8, NHEAD, BATCH), blk, 0, stream>>>(qb, kb, vb, grel, rk, rv, ab);
    gemm_out_mfma<<<dim3(8, 32), blk, 0, stream>>>(ab, wt + (size_t)3 * 512 * 512, bo, (float*)d_out);
}